// Round 5
// baseline (127.042 us; speedup 1.0000x reference)
//
#include <hip/hip_runtime.h>
#include <hip/hip_bf16.h>
#include <math.h>

// Problem constants
#define BB   16
#define CI   16
#define CO   16
#define HH   384
#define WW   384
#define HW   (HH * WW)

// Conv tiling: 32 wide x 16 tall output tile
#define TSW 32
#define TSH 16
#define HSW 34   // staged cols
#define HSH 18   // staged rows
#define NPX (HSW * HSH)  // 612 staged pixels

typedef __bf16 bfx8 __attribute__((ext_vector_type(8)));
typedef float  f32x4 __attribute__((ext_vector_type(4)));

// RNE pack of two f32 -> bf16x2 in a uint32 (lo = a, hi = b)
__device__ __forceinline__ uint32_t pack_bf16(float a, float b) {
  uint32_t ua = __builtin_bit_cast(uint32_t, a);
  uint32_t ub = __builtin_bit_cast(uint32_t, b);
  ua = (ua + 0x7FFFu + ((ua >> 16) & 1u)) >> 16;
  ub = (ub + 0x7FFFu + ((ub >> 16) & 1u)) >> 16;
  return ua | (ub << 16);
}

// ---------------------------------------------------------------------------
// Kernel 1a: pooled activity per (plane, bin).  2304 blocks x 256 threads.
// ---------------------------------------------------------------------------
__global__ __launch_bounds__(256) void pool_kernel(
    const float* __restrict__ x, float* __restrict__ pooled) {
  const int bx = blockIdx.x;
  const int plane = bx / 9;
  const int bin = bx - plane * 9;
  const int br = (bin / 3) * 128;
  const int bc4 = (bin % 3) * 32;
  const float4* xp = (const float4*)(x + (size_t)plane * HW);
  const int tid = threadIdx.x;

  int cnt = 0;
#pragma unroll
  for (int k = 0; k < 16; ++k) {
    const int idx = tid + k * 256;
    const int r = idx >> 5;
    const int c4 = idx & 31;
    const float4 v = xp[(size_t)(br + r) * (WW / 4) + bc4 + c4];
    cnt += (v.x >= 0.f) + (v.y >= 0.f) + (v.z >= 0.f) + (v.w >= 0.f);
  }
#pragma unroll
  for (int s = 32; s > 0; s >>= 1) cnt += __shfl_down(cnt, s);

  __shared__ int wsum[4];
  const int lane = tid & 63, wid = tid >> 6;
  if (lane == 0) wsum[wid] = cnt;
  __syncthreads();
  if (tid == 0) {
    int t = wsum[0] + wsum[1] + wsum[2] + wsum[3];
    pooled[bx] = (float)t * (1.f / 16384.f);
  }
}

// ---------------------------------------------------------------------------
// Kernel 1b: softmax+sigmoid finish. 1 block x 256 threads (1 per plane).
// ---------------------------------------------------------------------------
__global__ __launch_bounds__(256) void att_finish(
    const float* __restrict__ pooled, float* __restrict__ att) {
  const int plane = threadIdx.x;
  float v[9];
#pragma unroll
  for (int k = 0; k < 9; ++k) v[k] = pooled[plane * 9 + k];
  float m = v[0];
#pragma unroll
  for (int k = 1; k < 9; ++k) m = fmaxf(m, v[k]);
  float e[9], s = 0.f;
#pragma unroll
  for (int k = 0; k < 9; ++k) { e[k] = expf(v[k] - m); s += e[k]; }
  const float inv = 1.f / s;
#pragma unroll
  for (int k = 0; k < 9; ++k) {
    const float a = 9.f * e[k] * inv - 1.f;
    att[plane * 9 + k] = 1.f + 1.f / (1.f + expf(-a));
  }
}

// ---------------------------------------------------------------------------
// Kernel 2: bf16 MFMA implicit-GEMM conv.
// D[16 cout][16 px] per mfma_f32_16x16x32_bf16; K = pos*16 + ci, padded 160.
// LDS x-tile: [18 rows][34 cols][16ci] bf16, 16B-half XOR-swizzled by bit2(cc).
// 24.7 KB LDS -> 6 blocks/CU. Wave wv: rows 4wv..4wv+3, 2 col-groups each.
// ---------------------------------------------------------------------------
__global__ __launch_bounds__(256) void conv_kernel(
    const float* __restrict__ x, const float* __restrict__ Wt,
    const float* __restrict__ att, float* __restrict__ y) {
  const int b   = blockIdx.z;
  const int gx0 = blockIdx.x * TSW;
  const int gy0 = blockIdx.y * TSH;
  const int tid = threadIdx.x;

  __shared__ __align__(16) uint32_t sx[NPX * 8];   // 19,584 B
  __shared__ __align__(16) uint32_t sw[CO * 80];   //  5,120 B

  const float* xb = x + (size_t)b * CI * HW;

  // --- modulated weights -> sw[cout][k/2] packed bf16 pairs, k = pos*16+ci ---
#pragma unroll
  for (int i = 0; i < 5; ++i) {
    const int idx  = tid + 256 * i;  // 0..1279
    const int cout = idx / 80;
    const int kp   = idx - cout * 80;
    const int k0 = 2 * kp, k1 = 2 * kp + 1;
    const int p0 = k0 >> 4, ci0 = k0 & 15;
    const int p1 = k1 >> 4, ci1 = k1 & 15;
    float v0 = 0.f, v1 = 0.f;
    if (p0 < 9) v0 = Wt[(cout * CI + ci0) * 9 + p0] * att[(b * CI + ci0) * 9 + p0];
    if (p1 < 9) v1 = Wt[(cout * CI + ci1) * 9 + p1] * att[(b * CI + ci1) * 9 + p1];
    sw[cout * 80 + kp] = pack_bf16(v0, v1);
  }

  // --- stage x tile: pixel-major, 16 ci innermost (bf16), swizzled halves ---
#pragma unroll
  for (int it = 0; it < 3; ++it) {
    const int pix = tid + 256 * it;
    if (pix < NPX) {
      const int rr = pix / HSW;
      const int cc = pix - rr * HSW;
      const int gr = gy0 - 1 + rr;
      const int gc = gx0 - 1 + cc;
      uint32_t pk[8];
      if (((unsigned)gr < (unsigned)HH) && ((unsigned)gc < (unsigned)WW)) {
        const float* px = xb + (size_t)gr * WW + gc;
#pragma unroll
        for (int i = 0; i < 8; ++i) {
          const float v0 = px[(size_t)(2 * i) * HW];
          const float v1 = px[(size_t)(2 * i + 1) * HW];
          pk[i] = pack_bf16(v0, v1);
        }
      } else {
#pragma unroll
        for (int i = 0; i < 8; ++i) pk[i] = 0u;
      }
      const int s = (cc >> 2) & 1;  // swizzle: half index ^= bit2(cc)
      uint32_t* dst = &sx[pix * 8];
      uint4 lo, hi;
      lo.x = pk[0]; lo.y = pk[1]; lo.z = pk[2]; lo.w = pk[3];
      hi.x = pk[4]; hi.y = pk[5]; hi.z = pk[6]; hi.w = pk[7];
      *(uint4*)(dst + 4 * s)       = lo;  // ci 0-7
      *(uint4*)(dst + 4 * (1 - s)) = hi;  // ci 8-15
    }
  }
  __syncthreads();

  const int lane = tid & 63;
  const int wv   = tid >> 6;         // wave 0..3
  const int cpix = lane & 15;        // pixel col within group / A row (cout)
  const int h4   = lane >> 4;        // 0..3: A k-group; D row group
  const int hB   = h4 & 1;           // B ci-half
  const int pp   = lane >> 5;        // B pos parity

  // A fragments: Wmod[cout=cpix][k chunk q], 8 consecutive k each
  bfx8 aw[5];
  const char* swb = (const char*)sw;
#pragma unroll
  for (int q = 0; q < 5; ++q)
    aw[q] = *(const bfx8*)(swb + cpix * 320 + q * 64 + h4 * 16);

  // B per-lane byte offsets into sx for each K-chunk
  int Lq[5];
#pragma unroll
  for (int q = 0; q < 5; ++q) {
    int p = 2 * q + pp;
    if (p > 8) p = 8;                // k>=144: weights are zero; clamp addr
    const int dy = p / 3, dx = p - 3 * dy;
    const int ccl = cpix + dx;       // bit2(ccl+16) == bit2(ccl)
    const int swz = (ccl >> 2) & 1;
    Lq[q] = (dy * HSW + ccl) * 32 + 16 * (hB ^ swz);
  }

  const char* sxb = (const char*)sx;
  float* yb = y + ((size_t)b * CO + h4 * 4) * HW + (size_t)gy0 * WW + gx0 + cpix;

#pragma unroll 2
  for (int ri = 0; ri < 4; ++ri) {
    const int r = wv * 4 + ri;
    const int gbase = (r * HSW) * 32;
    f32x4 a0 = {0.f, 0.f, 0.f, 0.f};
    f32x4 a1 = {0.f, 0.f, 0.f, 0.f};
#pragma unroll
    for (int q = 0; q < 5; ++q) {
      const bfx8 b0 = *(const bfx8*)(sxb + gbase + Lq[q]);
      const bfx8 b1 = *(const bfx8*)(sxb + gbase + 512 + Lq[q]);  // c0 = 16
      a0 = __builtin_amdgcn_mfma_f32_16x16x32_bf16(aw[q], b0, a0, 0, 0, 0);
      a1 = __builtin_amdgcn_mfma_f32_16x16x32_bf16(aw[q], b1, a1, 0, 0, 0);
    }
    float* yr = yb + (size_t)r * WW;
#pragma unroll
    for (int j = 0; j < 4; ++j) {
      yr[(size_t)j * HW]      = a0[j];
      yr[(size_t)j * HW + 16] = a1[j];
    }
  }
}

// ---------------------------------------------------------------------------
extern "C" void kernel_launch(void* const* d_in, const int* in_sizes, int n_in,
                              void* d_out, int out_size, void* d_ws,
                              size_t ws_size, hipStream_t stream) {
  const float* x  = (const float*)d_in[0];
  const float* Wt = (const float*)d_in[1];
  float* y      = (float*)d_out;
  float* pooled = (float*)d_ws;         // 2304 floats
  float* att    = (float*)d_ws + 4096;  // 2304 floats

  pool_kernel<<<dim3(BB * CI * 9), dim3(256), 0, stream>>>(x, pooled);
  att_finish<<<dim3(1), dim3(256), 0, stream>>>(pooled, att);
  conv_kernel<<<dim3(WW / TSW, HH / TSH, BB), dim3(256), 0, stream>>>(
      x, Wt, att, y);
}